// Round 14
// baseline (215.489 us; speedup 1.0000x reference)
//
#include <hip/hip_runtime.h>
#include <hip/hip_bf16.h>

#define QSCALE 44.0f

// ---------- helpers ----------
__device__ __forceinline__ unsigned short f2bf(float f) {
    unsigned u = __float_as_uint(f);
    unsigned r = (u + 0x7fffu + ((u >> 16) & 1u)) >> 16;   // RNE
    return (unsigned short)r;
}
__device__ __forceinline__ float bfu(unsigned short s) {
    return __uint_as_float(((unsigned)s) << 16);
}

// int8 dot over one dword pair: acc += w[i] * relu(a_i + b_i)
__device__ __forceinline__ float dot4_i8(unsigned ax, unsigned bx, const float* w) {
    float acc = 0.f;
#pragma unroll
    for (int i = 0; i < 4; ++i) {
        int va = (int)(char)(ax >> (8 * i));
        int vb = (int)(char)(bx >> (8 * i));
        acc += w[i] * (float)max(va + vb, 0);
    }
    return acc;
}

__device__ __forceinline__ float dot16_i8(const uint4 a, const uint4 b, const float* w2r) {
    float acc;
    acc  = dot4_i8(a.x, b.x, w2r + 0);
    acc += dot4_i8(a.y, b.y, w2r + 4);
    acc += dot4_i8(a.z, b.z, w2r + 8);
    acc += dot4_i8(a.w, b.w, w2r + 12);
    return acc;
}

// ---------- kernel 1: persistent node projection + int8 quantize + agg zero (R12-proven) ----------
__global__ __launch_bounds__(256) void proj_kernel(
    const float* __restrict__ x, const float* __restrict__ w1, const float* __restrict__ b1,
    unsigned char* __restrict__ P, unsigned long long* __restrict__ agg, int N)
{
    __shared__ unsigned short wl[64 * 256];  // 32 KB, persistent across tiles
    __shared__ float xs[32 * 64];            // 8 KB, reloaded per tile
    const int t = threadIdx.x;

    for (int i = t; i < 64 * 256; i += 256) {
        int k = i >> 8, j = i & 255;
        float w = (j < 128) ? w1[k * 128 + j] : w1[(64 + k) * 128 + (j - 128)];
        wl[i] = f2bf(w);
    }

    const int jg = t & 63;
    const int ng = t >> 6;
    const int j0 = jg * 4;

    float bb[4] = {0.f, 0.f, 0.f, 0.f};
    if (j0 < 128) {
#pragma unroll
        for (int c = 0; c < 4; ++c) bb[c] = b1[j0 + c];
    }

    const int ntiles = (N + 31) / 32;
    for (int tile = blockIdx.x; tile < ntiles; tile += gridDim.x) {
        const int n0 = tile * 32;

        __syncthreads();   // protect xs from previous iteration's readers (covers wl on iter 0)
        if (t < 32) {
            int n = n0 + t;
            if (n < N) agg[n] = 0ull;
        }
        for (int i = t; i < 32 * 64; i += 256) {
            int n = n0 + (i >> 6);
            xs[i] = (n < N) ? x[(size_t)n * 64 + (i & 63)] : 0.f;
        }
        __syncthreads();

        float acc[8][4];
#pragma unroll
        for (int i = 0; i < 8; ++i)
#pragma unroll
            for (int c = 0; c < 4; ++c) acc[i][c] = 0.f;

        for (int k = 0; k < 64; k += 4) {
            float wv[4][4];
#pragma unroll
            for (int kk = 0; kk < 4; ++kk) {
                ushort4 wu = *(const ushort4*)&wl[(k + kk) * 256 + j0];
                wv[kk][0] = bfu(wu.x); wv[kk][1] = bfu(wu.y);
                wv[kk][2] = bfu(wu.z); wv[kk][3] = bfu(wu.w);
            }
#pragma unroll
            for (int i = 0; i < 8; ++i) {
                const float4 xv = *(const float4*)&xs[(ng * 8 + i) * 64 + k];
#pragma unroll
                for (int c = 0; c < 4; ++c)
                    acc[i][c] += xv.x * wv[0][c] + xv.y * wv[1][c] + xv.z * wv[2][c] + xv.w * wv[3][c];
            }
        }

#pragma unroll
        for (int i = 0; i < 8; ++i) {
            int n = n0 + ng * 8 + i;
            if (n < N) {
                unsigned pk = 0;
#pragma unroll
                for (int c = 0; c < 4; ++c) {
                    float v = (acc[i][c] + bb[c]) * QSCALE;
                    int q = __float2int_rn(fminf(fmaxf(v, -127.f), 127.f));
                    pk |= ((unsigned)(q & 0xff)) << (8 * c);
                }
                *(unsigned*)(P + (size_t)n * 256 + j0) = pk;
            }
        }
    }
}

// ---------- kernel 2: edge logit, 2 edges per 8-lane slot (4 gathers in flight) ----------
__global__ __launch_bounds__(256) void edge_logit_kernel(
    const unsigned char* __restrict__ P, const int* __restrict__ ei,
    const float* __restrict__ y,
    const float* __restrict__ w2, const float* __restrict__ b2,
    float* __restrict__ elog, unsigned long long* __restrict__ agg, int E)
{
    const int lane = threadIdx.x & 7;
    float w2r[16];
#pragma unroll
    for (int c = 0; c < 16; ++c) w2r[c] = w2[lane * 16 + c] * (1.0f / QSCALE);
    const float b2s = b2[0];

    const int slot = (blockIdx.x * 256 + threadIdx.x) >> 3;
    const int nslots = (gridDim.x * 256) >> 3;
    const int step = nslots * 2;

    // e0 is always even and E is even, so e0 < E implies e0+1 < E.
    for (int e0 = slot * 2; e0 < E; e0 += step) {
        const int2 ss = *(const int2*)&ei[e0];        // src pair
        const int2 dd = *(const int2*)&ei[E + e0];    // dst pair

        const uint4 a0 = *(const uint4*)(P + (size_t)ss.x * 256 + lane * 16);
        const uint4 b0 = *(const uint4*)(P + (size_t)dd.x * 256 + 128 + lane * 16);
        const uint4 a1 = *(const uint4*)(P + (size_t)ss.y * 256 + lane * 16);
        const uint4 b1 = *(const uint4*)(P + (size_t)dd.y * 256 + 128 + lane * 16);

        float acc0 = dot16_i8(a0, b0, w2r);
        float acc1 = dot16_i8(a1, b1, w2r);

        acc0 += __shfl_xor(acc0, 1);  acc1 += __shfl_xor(acc1, 1);
        acc0 += __shfl_xor(acc0, 2);  acc1 += __shfl_xor(acc1, 2);
        acc0 += __shfl_xor(acc0, 4);  acc1 += __shfl_xor(acc1, 4);

        if (lane == 0) {
            float ev = __expf(acc0 + b2s);
            elog[e0] = ev;
            float flo = fminf(ev * 65536.f, 1.0e9f);
            float fhi = fmaxf(fminf(y[ss.x] * ev * 16384.f, 1.0e9f), -1.0e9f);
            unsigned int qlo = (unsigned int)__float2int_rn(flo);
            int          qhi = __float2int_rn(fhi);
            atomicAdd(&agg[dd.x],
                ((unsigned long long)(unsigned int)qhi << 32) | (unsigned long long)qlo);
        } else if (lane == 4) {
            float ev = __expf(acc1 + b2s);
            elog[e0 + 1] = ev;
            float flo = fminf(ev * 65536.f, 1.0e9f);
            float fhi = fmaxf(fminf(y[ss.y] * ev * 16384.f, 1.0e9f), -1.0e9f);
            unsigned int qlo = (unsigned int)__float2int_rn(flo);
            int          qhi = __float2int_rn(fhi);
            atomicAdd(&agg[dd.y],
                ((unsigned long long)(unsigned int)qhi << 32) | (unsigned long long)qlo);
        }
    }
}

// ---------- kernel 3: decode agg -> yhat + inv_d  (R10-exact) ----------
__global__ void node_decode_kernel(const unsigned long long* __restrict__ agg,
                                   float* __restrict__ inv_d,
                                   float* __restrict__ yhat, int N) {
    int i = blockIdx.x * 256 + threadIdx.x;
    if (i >= N) return;
    unsigned long long v = agg[i];
    unsigned int lo = (unsigned int)(v & 0xffffffffull);
    int          hi = (int)(v >> 32);
    if (lo != 0u) {
        float flo = (float)lo;
        yhat[i]  = 4.0f * (float)hi / flo;   // (hi/2^14)/(lo/2^16)
        inv_d[i] = 65536.0f / flo;           // 1/denom
    } else {
        yhat[i]  = 0.f;
        inv_d[i] = 0.f;
    }
}

// ---------- kernel 4: alpha = ev * inv_d[dst]  (R10-exact) ----------
__global__ __launch_bounds__(256) void alpha_norm_kernel(
    const int* __restrict__ ei, float* __restrict__ elog,
    const float* __restrict__ inv_d, int E)
{
    int e = blockIdx.x * 256 + threadIdx.x;
    if (e >= E) return;
    int d = ei[E + e];
    elog[e] = elog[e] * inv_d[d];
}

extern "C" void kernel_launch(void* const* d_in, const int* in_sizes, int n_in,
                              void* d_out, int out_size, void* d_ws, size_t ws_size,
                              hipStream_t stream) {
    const float* x  = (const float*)d_in[0];
    const float* y  = (const float*)d_in[1];
    const int*   ei = (const int*)d_in[2];
    const float* w1 = (const float*)d_in[3];
    const float* b1 = (const float*)d_in[4];
    const float* w2 = (const float*)d_in[5];
    const float* b2 = (const float*)d_in[6];

    const int N = in_sizes[1];
    const int E = in_sizes[2] / 2;

    float* out  = (float*)d_out;
    float* yhat = out;          // [N]
    float* elog = out + N;      // [E] — exp values, then alpha in place

    char* ws = (char*)d_ws;
    unsigned char* P = (unsigned char*)ws;                         // N*256 int8 = 12.8 MB
    size_t Pbytes = (size_t)N * 256;
    unsigned long long* agg = (unsigned long long*)(ws + Pbytes);  // N u64
    float* inv_d = (float*)(ws + Pbytes + (size_t)N * 8);          // N f32

    proj_kernel<<<512, 256, 0, stream>>>(x, w1, b1, P, agg, N);
    edge_logit_kernel<<<2048, 256, 0, stream>>>(P, ei, y, w2, b2, elog, agg, E);
    node_decode_kernel<<<(N + 255) / 256, 256, 0, stream>>>(agg, inv_d, yhat, N);
    alpha_norm_kernel<<<(E + 255) / 256, 256, 0, stream>>>(ei, elog, inv_d, E);
}

// Round 15
// 210.331 us; speedup vs baseline: 1.0245x; 1.0245x over previous
//
#include <hip/hip_runtime.h>
#include <hip/hip_bf16.h>

#define QSCALE 44.0f

// ---------- helpers ----------
__device__ __forceinline__ unsigned short f2bf(float f) {
    unsigned u = __float_as_uint(f);
    unsigned r = (u + 0x7fffu + ((u >> 16) & 1u)) >> 16;   // RNE
    return (unsigned short)r;
}
__device__ __forceinline__ float bfu(unsigned short s) {
    return __uint_as_float(((unsigned)s) << 16);
}

// int8 dot over one dword pair: acc += w[i] * relu(a_i + b_i)
__device__ __forceinline__ float dot4_i8(unsigned ax, unsigned bx, const float* w) {
    float acc = 0.f;
#pragma unroll
    for (int i = 0; i < 4; ++i) {
        int va = (int)(char)(ax >> (8 * i));
        int vb = (int)(char)(bx >> (8 * i));
        acc += w[i] * (float)max(va + vb, 0);
    }
    return acc;
}

// ---------- kernel 1: persistent node projection + int8 quantize + agg zero (R12-proven) ----------
__global__ __launch_bounds__(256) void proj_kernel(
    const float* __restrict__ x, const float* __restrict__ w1, const float* __restrict__ b1,
    unsigned char* __restrict__ P, unsigned long long* __restrict__ agg, int N)
{
    __shared__ unsigned short wl[64 * 256];  // 32 KB, persistent across tiles
    __shared__ float xs[32 * 64];            // 8 KB, reloaded per tile
    const int t = threadIdx.x;

    for (int i = t; i < 64 * 256; i += 256) {
        int k = i >> 8, j = i & 255;
        float w = (j < 128) ? w1[k * 128 + j] : w1[(64 + k) * 128 + (j - 128)];
        wl[i] = f2bf(w);
    }

    const int jg = t & 63;
    const int ng = t >> 6;
    const int j0 = jg * 4;

    float bb[4] = {0.f, 0.f, 0.f, 0.f};
    if (j0 < 128) {
#pragma unroll
        for (int c = 0; c < 4; ++c) bb[c] = b1[j0 + c];
    }

    const int ntiles = (N + 31) / 32;
    for (int tile = blockIdx.x; tile < ntiles; tile += gridDim.x) {
        const int n0 = tile * 32;

        __syncthreads();   // protect xs from previous iteration's readers (covers wl on iter 0)
        if (t < 32) {
            int n = n0 + t;
            if (n < N) agg[n] = 0ull;
        }
        for (int i = t; i < 32 * 64; i += 256) {
            int n = n0 + (i >> 6);
            xs[i] = (n < N) ? x[(size_t)n * 64 + (i & 63)] : 0.f;
        }
        __syncthreads();

        float acc[8][4];
#pragma unroll
        for (int i = 0; i < 8; ++i)
#pragma unroll
            for (int c = 0; c < 4; ++c) acc[i][c] = 0.f;

        for (int k = 0; k < 64; k += 4) {
            float wv[4][4];
#pragma unroll
            for (int kk = 0; kk < 4; ++kk) {
                ushort4 wu = *(const ushort4*)&wl[(k + kk) * 256 + j0];
                wv[kk][0] = bfu(wu.x); wv[kk][1] = bfu(wu.y);
                wv[kk][2] = bfu(wu.z); wv[kk][3] = bfu(wu.w);
            }
#pragma unroll
            for (int i = 0; i < 8; ++i) {
                const float4 xv = *(const float4*)&xs[(ng * 8 + i) * 64 + k];
#pragma unroll
                for (int c = 0; c < 4; ++c)
                    acc[i][c] += xv.x * wv[0][c] + xv.y * wv[1][c] + xv.z * wv[2][c] + xv.w * wv[3][c];
            }
        }

#pragma unroll
        for (int i = 0; i < 8; ++i) {
            int n = n0 + ng * 8 + i;
            if (n < N) {
                unsigned pk = 0;
#pragma unroll
                for (int c = 0; c < 4; ++c) {
                    float v = (acc[i][c] + bb[c]) * QSCALE;
                    int q = __float2int_rn(fminf(fmaxf(v, -127.f), 127.f));
                    pk |= ((unsigned)(q & 0xff)) << (8 * c);
                }
                *(unsigned*)(P + (size_t)n * 256 + j0) = pk;
            }
        }
    }
}

// ---------- kernel 2: edge logit (R13-exact single-edge form, proven 85.5 us) ----------
// 8 lanes/edge; each lane loads 16 int8 from ps and pd (uint4 = 16B each side).
__global__ __launch_bounds__(256) void edge_logit_kernel(
    const unsigned char* __restrict__ P, const int* __restrict__ ei,
    const float* __restrict__ y,
    const float* __restrict__ w2, const float* __restrict__ b2,
    float* __restrict__ elog, unsigned long long* __restrict__ agg, int E)
{
    const int lane = threadIdx.x & 7;
    float w2r[16];
#pragma unroll
    for (int c = 0; c < 16; ++c) w2r[c] = w2[lane * 16 + c] * (1.0f / QSCALE);
    const float b2s = b2[0];

    const int slot = (blockIdx.x * 256 + threadIdx.x) >> 3;
    const int nslots = (gridDim.x * 256) >> 3;

    for (int e = slot; e < E; e += nslots) {
        const int s = ei[e];
        const int d = ei[E + e];
        const uint4 a = *(const uint4*)(P + (size_t)s * 256 + lane * 16);
        const uint4 b = *(const uint4*)(P + (size_t)d * 256 + 128 + lane * 16);

        float acc;
        acc  = dot4_i8(a.x, b.x, w2r + 0);
        acc += dot4_i8(a.y, b.y, w2r + 4);
        acc += dot4_i8(a.z, b.z, w2r + 8);
        acc += dot4_i8(a.w, b.w, w2r + 12);

        acc += __shfl_xor(acc, 1);
        acc += __shfl_xor(acc, 2);
        acc += __shfl_xor(acc, 4);

        if (lane == 0) {
            float ev = __expf(acc + b2s);
            elog[e] = ev;
            // packed fixed-point: lo = ev*2^16 (u32), hi = y[s]*ev*2^14 (i32)
            float flo = fminf(ev * 65536.f, 1.0e9f);
            float fhi = fmaxf(fminf(y[s] * ev * 16384.f, 1.0e9f), -1.0e9f);
            unsigned int qlo = (unsigned int)__float2int_rn(flo);
            int          qhi = __float2int_rn(fhi);
            unsigned long long packed =
                ((unsigned long long)(unsigned int)qhi << 32) | (unsigned long long)qlo;
            atomicAdd(&agg[d], packed);
        }
    }
}

// ---------- kernel 3: decode agg -> yhat + inv_d  (R10-exact) ----------
__global__ void node_decode_kernel(const unsigned long long* __restrict__ agg,
                                   float* __restrict__ inv_d,
                                   float* __restrict__ yhat, int N) {
    int i = blockIdx.x * 256 + threadIdx.x;
    if (i >= N) return;
    unsigned long long v = agg[i];
    unsigned int lo = (unsigned int)(v & 0xffffffffull);
    int          hi = (int)(v >> 32);
    if (lo != 0u) {
        float flo = (float)lo;
        yhat[i]  = 4.0f * (float)hi / flo;   // (hi/2^14)/(lo/2^16)
        inv_d[i] = 65536.0f / flo;           // 1/denom
    } else {
        yhat[i]  = 0.f;
        inv_d[i] = 0.f;
    }
}

// ---------- kernel 4: alpha = ev * inv_d[dst], 4 edges/thread with 16B loads ----------
__global__ __launch_bounds__(256) void alpha_norm_kernel(
    const int* __restrict__ ei, float* __restrict__ elog,
    const float* __restrict__ inv_d, int E)
{
    const int base = (blockIdx.x * 256 + threadIdx.x) * 4;
    if (base + 3 < E) {
        const int4   d4  = *(const int4*)&ei[E + base];
        float4       ev4 = *(const float4*)&elog[base];
        ev4.x *= inv_d[d4.x];
        ev4.y *= inv_d[d4.y];
        ev4.z *= inv_d[d4.z];
        ev4.w *= inv_d[d4.w];
        *(float4*)&elog[base] = ev4;
    } else {
        for (int e = base; e < E; ++e)
            elog[e] = elog[e] * inv_d[ei[E + e]];
    }
}

extern "C" void kernel_launch(void* const* d_in, const int* in_sizes, int n_in,
                              void* d_out, int out_size, void* d_ws, size_t ws_size,
                              hipStream_t stream) {
    const float* x  = (const float*)d_in[0];
    const float* y  = (const float*)d_in[1];
    const int*   ei = (const int*)d_in[2];
    const float* w1 = (const float*)d_in[3];
    const float* b1 = (const float*)d_in[4];
    const float* w2 = (const float*)d_in[5];
    const float* b2 = (const float*)d_in[6];

    const int N = in_sizes[1];
    const int E = in_sizes[2] / 2;

    float* out  = (float*)d_out;
    float* yhat = out;          // [N]
    float* elog = out + N;      // [E] — exp values, then alpha in place

    char* ws = (char*)d_ws;
    unsigned char* P = (unsigned char*)ws;                         // N*256 int8 = 12.8 MB
    size_t Pbytes = (size_t)N * 256;
    unsigned long long* agg = (unsigned long long*)(ws + Pbytes);  // N u64
    float* inv_d = (float*)(ws + Pbytes + (size_t)N * 8);          // N f32

    proj_kernel<<<512, 256, 0, stream>>>(x, w1, b1, P, agg, N);
    edge_logit_kernel<<<2048, 256, 0, stream>>>(P, ei, y, w2, b2, elog, agg, E);
    node_decode_kernel<<<(N + 255) / 256, 256, 0, stream>>>(agg, inv_d, yhat, N);
    alpha_norm_kernel<<<(E / 4 + 255) / 256, 256, 0, stream>>>(ei, elog, inv_d, E);
}